// Round 6
// baseline (614.966 us; speedup 1.0000x reference)
//
#include <hip/hip_runtime.h>
#include <cstdint>

#define B_ 8
#define A_ 120000
#define C_ 80
#define M_ 24

// ws layout (floats): [0..7] cls_sum[b], [8..15] reg_sum[b], [16..23] n_pos[b],
//                     [32 .. 32+B_*A_) per-anchor mask (0 = ignored, 1 = contributes)
#define WS_MASK_OFF 32

// ---------------- Kernel 1: anchor assignment + reg loss + pos corrections ----------------
__global__ __launch_bounds__(256, 4) void assign_k(
    const float* __restrict__ cls,
    const float* __restrict__ regs,
    const float* __restrict__ anchors,
    const float* __restrict__ annots,
    float* __restrict__ ws)
{
    const int b   = blockIdx.y;
    const int tid = threadIdx.x;
    const int a   = blockIdx.x * 256 + tid;

    __shared__ float s_annot[M_ * 5];
    __shared__ float s_redc[4], s_redr[4], s_redp[4];

    if (tid < M_ * 5) s_annot[tid] = annots[b * M_ * 5 + tid];
    __syncthreads();

    float cls_part = 0.0f, reg_part = 0.0f, pos_part = 0.0f;
    const float PLO = 1e-4f, PHI = 1.0f - 1e-4f;

    if (a < A_) {
        const float4 ab = *reinterpret_cast<const float4*>(anchors + (size_t)a * 4);
        const float ax1 = ab.x, ay1 = ab.y, ax2 = ab.z, ay2 = ab.w;
        const float aw  = ax2 - ax1, ah = ay2 - ay1;
        const float acx = ax1 + 0.5f * aw, acy = ay1 + 0.5f * ah;
        const float a_area = aw * ah;

        float best = -1e30f;
        int bestm = 0;
        #pragma unroll
        for (int m = 0; m < M_; ++m) {
            const float gx1 = s_annot[m * 5 + 0], gy1 = s_annot[m * 5 + 1];
            const float gx2 = s_annot[m * 5 + 2], gy2 = s_annot[m * 5 + 3];
            const float lab = s_annot[m * 5 + 4];
            const float g_area = (gx2 - gx1) * (gy2 - gy1);
            float iw = fminf(ax2, gx2) - fmaxf(ax1, gx1); iw = fmaxf(iw, 0.0f);
            float ih = fminf(ay2, gy2) - fmaxf(ay1, gy1); ih = fmaxf(ih, 0.0f);
            const float inter = iw * ih;
            const float uni = fmaxf(a_area + g_area - inter, 1e-6f);
            float iou = inter * __builtin_amdgcn_rcpf(uni);   // ~1e-7 rel err
            iou = (lab >= 0.0f) ? iou : -1.0f;
            if (iou > best) { best = iou; bestm = m; }        // strict > == first-max argmax
        }

        const bool pos    = best >= 0.5f;
        const bool ignore = (best >= 0.4f) && !pos;
        const int  lab    = (int)s_annot[bestm * 5 + 4];
        ws[WS_MASK_OFF + (size_t)b * A_ + a] = ignore ? 0.0f : 1.0f;

        if (pos) {
            pos_part = 1.0f;
            // smooth-L1 regression
            const float4 rv = *reinterpret_cast<const float4*>(regs + ((size_t)b * A_ + a) * 4);
            const float gx1 = s_annot[bestm * 5 + 0], gy1 = s_annot[bestm * 5 + 1];
            const float gx2 = s_annot[bestm * 5 + 2], gy2 = s_annot[bestm * 5 + 3];
            const float gw  = fmaxf(gx2 - gx1, 1.0f);
            const float gh  = fmaxf(gy2 - gy1, 1.0f);
            const float gcx = gx1 + 0.5f * (gx2 - gx1);
            const float gcy = gy1 + 0.5f * (gy2 - gy1);
            const float inv_aw = __builtin_amdgcn_rcpf(aw);
            const float inv_ah = __builtin_amdgcn_rcpf(ah);
            const float t0 = (gcx - acx) * inv_aw * 10.0f;
            const float t1 = (gcy - acy) * inv_ah * 10.0f;
            const float t2 = __logf(gw * inv_aw) * 5.0f;
            const float t3 = __logf(gh * inv_ah) * 5.0f;
            const float d0 = fabsf(t0 - rv.x), d1 = fabsf(t1 - rv.y);
            const float d2 = fabsf(t2 - rv.z), d3 = fabsf(t3 - rv.w);
            const float th = 1.0f / 9.0f, sub = 0.5f / 9.0f;
            float s;
            s  = (d0 <= th) ? 4.5f * d0 * d0 : d0 - sub;
            s += (d1 <= th) ? 4.5f * d1 * d1 : d1 - sub;
            s += (d2 <= th) ? 4.5f * d2 * d2 : d2 - sub;
            s += (d3 <= th) ? 4.5f * d3 * d3 : d3 - sub;
            reg_part = s;

            // positive-class correction vs the stream kernel's negative baseline
            float p = cls[((size_t)b * A_ + a) * C_ + lab];
            p = fminf(fmaxf(p, PLO), PHI);
            const float q = 1.0f - p;
            cls_part = 0.25f * q * q * (-__logf(p)) - 0.75f * p * p * (-__logf(q));
        }
    }

    for (int off = 32; off > 0; off >>= 1) {
        cls_part += __shfl_down(cls_part, off, 64);
        reg_part += __shfl_down(reg_part, off, 64);
        pos_part += __shfl_down(pos_part, off, 64);
    }
    const int wid = tid >> 6;
    if ((tid & 63) == 0) { s_redc[wid] = cls_part; s_redr[wid] = reg_part; s_redp[wid] = pos_part; }
    __syncthreads();
    if (tid == 0) {
        atomicAdd(&ws[b],      s_redc[0] + s_redc[1] + s_redc[2] + s_redc[3]);
        atomicAdd(&ws[8 + b],  s_redr[0] + s_redr[1] + s_redr[2] + s_redr[3]);
        atomicAdd(&ws[16 + b], s_redp[0] + s_redp[1] + s_redp[2] + s_redp[3]);
    }
}

// ---------------- Kernel 2: pure streaming negative-baseline focal sum ----------------
// per element: 0.75 * p^2 * (-ln(1-p)), masked per anchor row. 5 fixed iterations,
// fully unrolled: 1875 blocks/image * 256 threads * 5 * 4 elems = 2.4M vec4 = A_*C_/4.
#define SB 1875
__global__ __launch_bounds__(256, 8) void stream_k(
    const float* __restrict__ cls,
    float* __restrict__ ws)
{
    const int b   = blockIdx.y;
    const int tid = threadIdx.x;
    const float4* cp4 = reinterpret_cast<const float4*>(cls + (size_t)b * A_ * C_);
    const float*  msk = ws + WS_MASK_OFF + (size_t)b * A_;
    const int base = blockIdx.x * (5 * 256);

    __shared__ float s_red[4];
    const float PHI = 1.0f - 1e-4f;
    float acc = 0.0f;

    #pragma unroll
    for (int k = 0; k < 5; ++k) {
        const int i = base + k * 256 + tid;       // vec4 index within image
        const float4 v = cp4[i];
        const float  m = msk[i / 20];             // 20 vec4s per anchor row (magic-mul)
        float c = 0.0f, p, q;
        p = fminf(v.x, PHI); q = 1.0f - p; c = fmaf(p * p, __log2f(q), c);
        p = fminf(v.y, PHI); q = 1.0f - p; c = fmaf(p * p, __log2f(q), c);
        p = fminf(v.z, PHI); q = 1.0f - p; c = fmaf(p * p, __log2f(q), c);
        p = fminf(v.w, PHI); q = 1.0f - p; c = fmaf(p * p, __log2f(q), c);
        acc = fmaf(m, c, acc);
    }

    for (int off = 32; off > 0; off >>= 1) acc += __shfl_down(acc, off, 64);
    const int wid = tid >> 6;
    if ((tid & 63) == 0) s_red[wid] = acc;
    __syncthreads();
    if (tid == 0) {
        const float NEG_SCALE = -0.75f * 0.69314718056f;   // p^2*log2(q) -> 0.75*p^2*(-ln q)
        atomicAdd(&ws[b], (s_red[0] + s_red[1] + s_red[2] + s_red[3]) * NEG_SCALE);
    }
}

__global__ void focal_final(const float* __restrict__ ws, float* __restrict__ out)
{
    if (threadIdx.x == 0) {
        float cm = 0.0f, rm = 0.0f;
        for (int b = 0; b < B_; ++b) {
            const float np = ws[16 + b];
            cm += ws[b] / fmaxf(np, 1.0f);
            rm += (np > 0.0f) ? ws[8 + b] / (np * 4.0f) : 0.0f;
        }
        out[0] = cm * (1.0f / B_);
        out[1] = rm * (1.0f / B_);
    }
}

extern "C" void kernel_launch(void* const* d_in, const int* in_sizes, int n_in,
                              void* d_out, int out_size, void* d_ws, size_t ws_size,
                              hipStream_t stream)
{
    const float* cls     = (const float*)d_in[0];
    const float* regs    = (const float*)d_in[1];
    const float* anchors = (const float*)d_in[2];
    const float* annots  = (const float*)d_in[3];
    float* ws  = (float*)d_ws;
    float* out = (float*)d_out;

    hipMemsetAsync(d_ws, 0, 24 * sizeof(float), stream);   // zero the 24 accumulators

    dim3 agrid((A_ + 255) / 256, B_);     // (469, 8)
    assign_k<<<agrid, 256, 0, stream>>>(cls, regs, anchors, annots, ws);

    dim3 sgrid(SB, B_);                   // (1875, 8): 1875*256*5*4 = 9.6M elems = A_*C_
    stream_k<<<sgrid, 256, 0, stream>>>(cls, ws);

    focal_final<<<1, 64, 0, stream>>>(ws, out);
}

// Round 7
// 427.255 us; speedup vs baseline: 1.4393x; 1.4393x over previous
//
#include <hip/hip_runtime.h>
#include <cstdint>

#define B_ 8
#define A_ 120000
#define C_ 80
#define M_ 24
#define APB 250                 // anchors per block; 120000/250 = 480 exact
#define P_  (A_ / APB)          // 480 blocks per image
#define NVB (APB * C_ / 4)      // 5000 float4s per block

// ws float layout (all plain stores, no atomics, no init needed):
//   [0      .. 3840)  cls partial per block  (slot = b*P_ + bx)
//   [3840   .. 7680)  reg partial per block
//   [7680   .. 11520) n_pos partial per block
#define PART_R 3840
#define PART_P 7680

__global__ __launch_bounds__(256) void focal_main(
    const float* __restrict__ cls,
    const float* __restrict__ regs,
    const float* __restrict__ anchors,
    const float* __restrict__ annots,
    float* __restrict__ ws)
{
    const int b   = blockIdx.y;
    const int a0  = blockIdx.x * APB;
    const int tid = threadIdx.x;

    __shared__ float s_annot[M_ * 5];
    __shared__ float s_mask[APB];          // 0 = ignored anchor, 1 = contributes
    __shared__ float s_redc[4], s_redr[4], s_redp[4];

    if (tid < M_ * 5) s_annot[tid] = annots[b * M_ * 5 + tid];
    __syncthreads();

    float cls_part = 0.0f, reg_part = 0.0f, pos_part = 0.0f;
    const float PLO = 1e-4f, PHI = 1.0f - 1e-4f;

    // ---- Phase 1: one anchor per thread (tid < 250) ----
    if (tid < APB) {
        const int a = a0 + tid;
        const float4 ab = *reinterpret_cast<const float4*>(anchors + (size_t)a * 4);
        const float ax1 = ab.x, ay1 = ab.y, ax2 = ab.z, ay2 = ab.w;
        const float aw  = ax2 - ax1, ah = ay2 - ay1;
        const float acx = ax1 + 0.5f * aw, acy = ay1 + 0.5f * ah;
        const float a_area = aw * ah;

        float best = -1e30f;
        int bestm = 0;
        #pragma unroll
        for (int m = 0; m < M_; ++m) {
            const float gx1 = s_annot[m * 5 + 0], gy1 = s_annot[m * 5 + 1];
            const float gx2 = s_annot[m * 5 + 2], gy2 = s_annot[m * 5 + 3];
            const float lab = s_annot[m * 5 + 4];
            const float g_area = (gx2 - gx1) * (gy2 - gy1);
            float iw = fminf(ax2, gx2) - fmaxf(ax1, gx1); iw = fmaxf(iw, 0.0f);
            float ih = fminf(ay2, gy2) - fmaxf(ay1, gy1); ih = fmaxf(ih, 0.0f);
            const float inter = iw * ih;
            const float uni = fmaxf(a_area + g_area - inter, 1e-6f);
            float iou = inter * __builtin_amdgcn_rcpf(uni);   // ~1e-7 rel err
            iou = (lab >= 0.0f) ? iou : -1.0f;
            if (iou > best) { best = iou; bestm = m; }        // strict > == first-max argmax
        }

        const bool pos    = best >= 0.5f;
        const bool ignore = (best >= 0.4f) && !pos;
        const int  lab    = (int)s_annot[bestm * 5 + 4];
        s_mask[tid] = ignore ? 0.0f : 1.0f;

        if (pos) {
            pos_part = 1.0f;
            // --- smooth-L1 regression ---
            const float4 rv = *reinterpret_cast<const float4*>(regs + ((size_t)b * A_ + a) * 4);
            const float gx1 = s_annot[bestm * 5 + 0], gy1 = s_annot[bestm * 5 + 1];
            const float gx2 = s_annot[bestm * 5 + 2], gy2 = s_annot[bestm * 5 + 3];
            const float gw  = fmaxf(gx2 - gx1, 1.0f);
            const float gh  = fmaxf(gy2 - gy1, 1.0f);
            const float gcx = gx1 + 0.5f * (gx2 - gx1);
            const float gcy = gy1 + 0.5f * (gy2 - gy1);
            const float inv_aw = __builtin_amdgcn_rcpf(aw);
            const float inv_ah = __builtin_amdgcn_rcpf(ah);
            const float t0 = (gcx - acx) * inv_aw * 10.0f;
            const float t1 = (gcy - acy) * inv_ah * 10.0f;
            const float t2 = __logf(gw * inv_aw) * 5.0f;
            const float t3 = __logf(gh * inv_ah) * 5.0f;
            const float d0 = fabsf(t0 - rv.x), d1 = fabsf(t1 - rv.y);
            const float d2 = fabsf(t2 - rv.z), d3 = fabsf(t3 - rv.w);
            const float th = 1.0f / 9.0f, sub = 0.5f / 9.0f;
            float s;
            s  = (d0 <= th) ? 4.5f * d0 * d0 : d0 - sub;
            s += (d1 <= th) ? 4.5f * d1 * d1 : d1 - sub;
            s += (d2 <= th) ? 4.5f * d2 * d2 : d2 - sub;
            s += (d3 <= th) ? 4.5f * d3 * d3 : d3 - sub;
            reg_part = s;

            // --- positive-class correction vs the negative baseline of phase 2 ---
            float p = cls[((size_t)b * A_ + a) * C_ + lab];
            p = fminf(fmaxf(p, PLO), PHI);
            const float q = 1.0f - p;
            cls_part = 0.25f * q * q * (-__logf(p)) - 0.75f * p * p * (-__logf(q));
        }
    }
    __syncthreads();   // s_mask ready

    // ---- Phase 2: branch-free negative baseline over the 250x80 slab ----
    const float4* cp4 = reinterpret_cast<const float4*>(cls + ((size_t)b * A_ + a0) * C_);
    const float NEG_SCALE = -0.75f * 0.69314718056f;   // p^2*log2(q) -> 0.75*p^2*(-ln q)
    #pragma unroll 4
    for (int i = tid; i < NVB; i += 256) {
        const float4 v = cp4[i];
        const int   al = i / 20;            // 20 vec4s per anchor row
        const float m  = s_mask[al];
        float c = 0.0f, p, q;
        p = fminf(v.x, PHI); q = 1.0f - p; c = fmaf(p * p, __log2f(q), c);
        p = fminf(v.y, PHI); q = 1.0f - p; c = fmaf(p * p, __log2f(q), c);
        p = fminf(v.z, PHI); q = 1.0f - p; c = fmaf(p * p, __log2f(q), c);
        p = fminf(v.w, PHI); q = 1.0f - p; c = fmaf(p * p, __log2f(q), c);
        cls_part = fmaf(m * c, NEG_SCALE, cls_part);
    }

    // ---- block reduce -> per-block partial stores (NO global atomics) ----
    for (int off = 32; off > 0; off >>= 1) {
        cls_part += __shfl_down(cls_part, off, 64);
        reg_part += __shfl_down(reg_part, off, 64);
        pos_part += __shfl_down(pos_part, off, 64);
    }
    const int wid = tid >> 6;
    if ((tid & 63) == 0) { s_redc[wid] = cls_part; s_redr[wid] = reg_part; s_redp[wid] = pos_part; }
    __syncthreads();
    if (tid == 0) {
        const int slot = b * P_ + blockIdx.x;
        ws[slot]          = s_redc[0] + s_redc[1] + s_redc[2] + s_redc[3];
        ws[PART_R + slot] = s_redr[0] + s_redr[1] + s_redr[2] + s_redr[3];
        ws[PART_P + slot] = s_redp[0] + s_redp[1] + s_redp[2] + s_redp[3];
    }
}

__global__ __launch_bounds__(256) void focal_final(const float* __restrict__ ws,
                                                   float* __restrict__ out)
{
    const int tid = threadIdx.x;
    __shared__ float sc[4], sr[4], sp[4];
    float cm = 0.0f, rm = 0.0f;

    for (int b = 0; b < B_; ++b) {
        float c = 0.0f, r = 0.0f, p = 0.0f;
        for (int bx = tid; bx < P_; bx += 256) {
            const int s = b * P_ + bx;
            c += ws[s];
            r += ws[PART_R + s];
            p += ws[PART_P + s];
        }
        for (int off = 32; off > 0; off >>= 1) {
            c += __shfl_down(c, off, 64);
            r += __shfl_down(r, off, 64);
            p += __shfl_down(p, off, 64);
        }
        const int wid = tid >> 6;
        if ((tid & 63) == 0) { sc[wid] = c; sr[wid] = r; sp[wid] = p; }
        __syncthreads();
        if (tid == 0) {
            const float ct = sc[0] + sc[1] + sc[2] + sc[3];
            const float rt = sr[0] + sr[1] + sr[2] + sr[3];
            const float pt = sp[0] + sp[1] + sp[2] + sp[3];
            cm += ct / fmaxf(pt, 1.0f);
            rm += (pt > 0.0f) ? rt / (pt * 4.0f) : 0.0f;
        }
        __syncthreads();
    }
    if (tid == 0) { out[0] = cm * 0.125f; out[1] = rm * 0.125f; }
}

extern "C" void kernel_launch(void* const* d_in, const int* in_sizes, int n_in,
                              void* d_out, int out_size, void* d_ws, size_t ws_size,
                              hipStream_t stream)
{
    const float* cls     = (const float*)d_in[0];
    const float* regs    = (const float*)d_in[1];
    const float* anchors = (const float*)d_in[2];
    const float* annots  = (const float*)d_in[3];
    float* ws  = (float*)d_ws;
    float* out = (float*)d_out;

    dim3 grid(P_, B_);   // (480, 8)
    focal_main<<<grid, 256, 0, stream>>>(cls, regs, anchors, annots, ws);
    focal_final<<<1, 256, 0, stream>>>(ws, out);
}